// Round 3
// baseline (2518.287 us; speedup 1.0000x reference)
//
#include <hip/hip_runtime.h>
#include <hip/hip_bf16.h>
#include <stdint.h>

#define N_NODES 16384
#define E_EDGES 131072
#define F_DIM 128
#define L_DIM 9
#define R_DIM 8
#define DOUT_DIM 1152
#define K_SEL 1024
#define HID_DIM 64
#define DA_DIM 64

// ---------------- fp32 GEMM: C = A(MxK)*B(KxN) [+ Add on first addW cols]
// 128x128 block tile, 256 threads, 8x8 micro tile, BK=16.
#define BM 128
#define BN 128
#define BK 16
__global__ __launch_bounds__(256) void gemm_f32(
    const float* __restrict__ A, int lda,
    const float* __restrict__ B, int ldb,
    float* __restrict__ C, int ldc,
    int M, int Nc, int Kc,
    const float* __restrict__ Add, int ldadd, int addW)
{
  __shared__ float As[BK][BM + 1];
  __shared__ float Bs[BK][BN];
  const int tid = threadIdx.x;
  const int tx = tid & 15, ty = tid >> 4;
  const int bm = blockIdx.y * BM, bn = blockIdx.x * BN;
  float acc[8][8];
#pragma unroll
  for (int i = 0; i < 8; i++)
#pragma unroll
    for (int j = 0; j < 8; j++) acc[i][j] = 0.f;

  for (int k0 = 0; k0 < Kc; k0 += BK) {
    const int ac = tid & 15, ar0 = tid >> 4;
#pragma unroll
    for (int rr = 0; rr < 8; rr++) {
      int row = ar0 + rr * 16;
      As[ac][row] = A[(size_t)(bm + row) * lda + k0 + ac];
    }
    const int bc = tid & 127, br0 = tid >> 7;
#pragma unroll
    for (int rr = 0; rr < 8; rr++) {
      int kr = br0 + rr * 2;
      Bs[kr][bc] = B[(size_t)(k0 + kr) * ldb + bn + bc];
    }
    __syncthreads();
#pragma unroll
    for (int kk = 0; kk < BK; kk++) {
      float a[8], b[8];
#pragma unroll
      for (int i = 0; i < 8; i++) a[i] = As[kk][ty * 8 + i];
#pragma unroll
      for (int j = 0; j < 8; j++) b[j] = Bs[kk][tx * 8 + j];
#pragma unroll
      for (int i = 0; i < 8; i++)
#pragma unroll
        for (int j = 0; j < 8; j++) acc[i][j] = fmaf(a[i], b[j], acc[i][j]);
    }
    __syncthreads();
  }
#pragma unroll
  for (int i = 0; i < 8; i++) {
    int row = bm + ty * 8 + i;
#pragma unroll
    for (int j = 0; j < 8; j++) {
      int col = bn + tx * 8 + j;
      float v = acc[i][j];
      if (Add != nullptr && col < addW) v += Add[(size_t)row * ldadd + col];
      C[(size_t)row * ldc + col] = v;
    }
  }
}

// ---------------- edge scatter: upd[dst,l,f] += sh[e,l] * hW[src,f] * (ef @ W_rad_l)[f]
__global__ __launch_bounds__(256) void scatter_kernel(
    const float* __restrict__ hW, const float* __restrict__ edge_sh,
    const float* __restrict__ edge_feats, const float* __restrict__ W_rad_l,
    const int* __restrict__ ei, float* __restrict__ upd)
{
  __shared__ float sWr[R_DIM * F_DIM];
  const int tid = threadIdx.x;
  for (int t = tid; t < R_DIM * F_DIM; t += 256) sWr[t] = W_rad_l[t];
  __syncthreads();
  const int f = tid & 127;
  const int sub = tid >> 7;
  const size_t e = (size_t)blockIdx.x * 2 + sub;
  const int s = ei[e], d = ei[E_EDGES + e];
  float rw = 0.f;
#pragma unroll
  for (int p = 0; p < R_DIM; p++)
    rw = fmaf(edge_feats[e * R_DIM + p], sWr[p * F_DIM + f], rw);
  const float tf = hW[(size_t)s * F_DIM + f] * rw;
  float* base = upd + (size_t)d * DOUT_DIM + f;
#pragma unroll
  for (int l = 0; l < L_DIM; l++)
    atomicAdd(base + l * F_DIM, edge_sh[e * L_DIM + l] * tf);
}

// ---------------- gating MLP on h_local[:, :F] (fp32, strided from d_out region 0)
__global__ __launch_bounds__(256) void gate_kernel(
    const float* __restrict__ hl, const float* __restrict__ W1,
    const float* __restrict__ b1, const float* __restrict__ W2,
    const float* __restrict__ b2, float* __restrict__ m_ws, float* __restrict__ m_out)
{
  __shared__ float sW1[F_DIM * HID_DIM];
  __shared__ float srow[4][F_DIM];
  const int tid = threadIdx.x;
  for (int t = tid; t < F_DIM * HID_DIM; t += 256) sW1[t] = W1[t];
  const int wave = tid >> 6, lane = tid & 63;
  const int n = blockIdx.x * 4 + wave;
  srow[wave][lane] = hl[(size_t)n * DOUT_DIM + lane];
  srow[wave][lane + 64] = hl[(size_t)n * DOUT_DIM + lane + 64];
  __syncthreads();
  float hid = b1[lane];
#pragma unroll 8
  for (int c = 0; c < F_DIM; c++) hid = fmaf(srow[wave][c], sW1[c * HID_DIM + lane], hid);
  hid = fmaxf(hid, 0.f);
  float v = hid * W2[lane];
#pragma unroll
  for (int off = 32; off > 0; off >>= 1) v += __shfl_down(v, off);
  if (lane == 0) {
    float mm = 1.f / (1.f + expf(-(v + b2[0])));
    m_ws[n] = mm;
    m_out[n] = mm;
  }
}

// ---------------- exact top-K + sort + rank. Single block, 1024 threads, 64KB LDS.
// key = (f32bits(m) << 14) | (16383 - idx)  (m>0 -> bit-monotone; ties -> lower idx)
__global__ __launch_bounds__(1024) void topk_kernel(
    const float* __restrict__ m_ws,
    unsigned long long* __restrict__ keys,
    int* __restrict__ master_idx, int* __restrict__ rank,
    float* __restrict__ mi_out)
{
  __shared__ unsigned long long s[8192];  // 64KB
  const int tid = threadIdx.x;
  for (int i = tid; i < N_NODES; i += 1024) {
    unsigned mb = __float_as_uint(m_ws[i]);
    keys[i] = (((unsigned long long)mb) << 14) | (unsigned long long)(16383 - i);
  }
  __syncthreads();
  for (int ch = 0; ch < 2; ch++) {
    unsigned long long* g = keys + ch * 8192;
    for (int i = tid; i < 8192; i += 1024) s[i] = g[i];
    __syncthreads();
    for (int k = 2; k <= 8192; k <<= 1) {
      for (int j = k >> 1; j > 0; j >>= 1) {
        for (int i = tid; i < 8192; i += 1024) {
          int ixj = i ^ j;
          if (ixj > i) {
            unsigned long long a = s[i], b = s[ixj];
            bool up = ((i & k) == 0);
            if (up ? (a < b) : (a > b)) { s[i] = b; s[ixj] = a; }
          }
        }
        __syncthreads();
      }
    }
    for (int i = tid; i < 8192; i += 1024) g[i] = s[i];
    __syncthreads();
  }
  // merge two top-1024 heads (desc ++ asc = bitonic) -> desc merge over 2048
  s[tid] = keys[tid];
  s[1024 + tid] = keys[8192 + (1023 - tid)];
  __syncthreads();
  for (int j = 1024; j > 0; j >>= 1) {
    for (int i = tid; i < 2048; i += 1024) {
      int ixj = i ^ j;
      if (ixj > i) {
        unsigned long long a = s[i], b = s[ixj];
        if (a < b) { s[i] = b; s[ixj] = a; }
      }
    }
    __syncthreads();
  }
  int myidx = 16383 - (int)(s[tid] & 0x3FFFull);
  __syncthreads();
  int* si = (int*)s;
  si[tid] = myidx;
  __syncthreads();
  for (int k = 2; k <= 1024; k <<= 1) {
    for (int j = k >> 1; j > 0; j >>= 1) {
      int i = tid, ixj = i ^ j;
      if (ixj > i) {
        int a = si[i], b = si[ixj];
        bool up = ((i & k) == 0);
        if (up ? (a > b) : (a < b)) { si[i] = b; si[ixj] = a; }
      }
      __syncthreads();
    }
  }
  int v = si[tid];
  master_idx[tid] = v;
  mi_out[tid] = (float)v;
  for (int i = tid; i < N_NODES; i += 1024) rank[i] = K_SEL;
  __syncthreads();
  rank[si[tid]] = tid;
}

// ---------------- induced adjacency among masters (u8)
__global__ __launch_bounds__(256) void adj_kernel(
    const int* __restrict__ ei, const int* __restrict__ rank, unsigned char* __restrict__ adjm)
{
  int e = blockIdx.x * 256 + threadIdx.x;
  int rs = rank[ei[e]];
  int rd = rank[ei[E_EDGES + e]];
  if (rs < K_SEL && rd < K_SEL) adjm[(size_t)rs * K_SEL + rd] = 1;  // benign same-value race
}

// ---------------- gather master rows (fp32 h_local in d_out) + positions
__global__ __launch_bounds__(128) void gather_kernel(
    const float* __restrict__ hl, const float* __restrict__ pos,
    const int* __restrict__ midx, float* __restrict__ h_m, float* __restrict__ pos_m)
{
  const int rI = blockIdx.x, t = threadIdx.x;
  const int mi = midx[rI];
  for (int c = t; c < DOUT_DIM; c += 128)
    h_m[(size_t)rI * DOUT_DIM + c] = hl[(size_t)mi * DOUT_DIM + c];
  if (t < 3) pos_m[rI * 3 + t] = pos[mi * 3 + t];
}

// ---------------- q / k projections from h_local[:, :F] at master rows
__global__ __launch_bounds__(128) void qk_kernel(
    const float* __restrict__ hl, const int* __restrict__ midx,
    const float* __restrict__ Wq, const float* __restrict__ Wk,
    float* __restrict__ q, float* __restrict__ kk)
{
  __shared__ float row[F_DIM];
  const int i = blockIdx.x, t = threadIdx.x;
  const int mi = midx[i];
  row[t] = hl[(size_t)mi * DOUT_DIM + t];
  __syncthreads();
  const int d = t & 63;
  const float* W = (t < 64) ? Wq : Wk;
  float acc = 0.f;
#pragma unroll 8
  for (int c = 0; c < F_DIM; c++) acc = fmaf(row[c], W[c * DA_DIM + d], acc);
  float* dst = (t < 64) ? q : kk;
  dst[(size_t)i * DA_DIM + d] = acc;
}

// ---------------- attention: A = sigmoid(q k^T / 8); emit A_virtual f32 + mask u8
__global__ __launch_bounds__(256) void attn_kernel(
    const float* __restrict__ q, const float* __restrict__ kk,
    unsigned char* __restrict__ maskA, float* __restrict__ Av)
{
  __shared__ float qs[16][DA_DIM], ks[16][DA_DIM];
  const int tx = threadIdx.x, ty = threadIdx.y;
  const int tid = ty * 16 + tx;
  const int i0 = blockIdx.y * 16, j0 = blockIdx.x * 16;
  for (int t = tid; t < 16 * DA_DIM; t += 256) {
    int rr = t >> 6, cc = t & 63;
    qs[rr][cc] = q[(size_t)(i0 + rr) * DA_DIM + cc];
    ks[rr][cc] = kk[(size_t)(j0 + rr) * DA_DIM + cc];
  }
  __syncthreads();
  float acc = 0.f;
#pragma unroll
  for (int d2 = 0; d2 < DA_DIM; d2++) acc = fmaf(qs[ty][d2], ks[tx][d2], acc);
  float sgl = 1.f / (1.f + expf(-acc * 0.125f));
  size_t o = (size_t)(i0 + ty) * K_SEL + (j0 + tx);
  bool big = sgl > 0.5f;
  maskA[o] = big ? 1 : 0;
  Av[o] = big ? sgl : 0.f;
}

// ---------------- hierarchical accumulation: upd_m[i,l,f] = sum_j sh[i,j,l]*tm[i,j,f]
__global__ __launch_bounds__(128) void hier_kernel(
    const float* __restrict__ hWn, const unsigned char* __restrict__ maskA,
    const unsigned char* __restrict__ adjm, const float* __restrict__ pos_m,
    const float* __restrict__ W_rad_h, float* __restrict__ upd_m)
{
  __shared__ float sW[R_DIM * F_DIM];
  const int i = blockIdx.x;
  const int f = threadIdx.x;
  for (int t = f; t < R_DIM * F_DIM; t += 128) sW[t] = W_rad_h[t];
  __syncthreads();
  const float pix = pos_m[i * 3 + 0], piy = pos_m[i * 3 + 1], piz = pos_m[i * 3 + 2];
  float acc[L_DIM];
#pragma unroll
  for (int l = 0; l < L_DIM; l++) acc[l] = 0.f;
  for (int j = 0; j < K_SEL; j++) {
    // A_rec[i,j] = adj_master[j,i] = (j!=i) & (adjI[j,i] | A[j,i]>.5 | A[i,j]>.5)
    bool e = (j != i) && (adjm[(size_t)j * K_SEL + i] | maskA[(size_t)j * K_SEL + i] |
                          maskA[(size_t)i * K_SEL + j]);
    if (!e) continue;
    float vx = pos_m[j * 3 + 0] - pix;
    float vy = pos_m[j * 3 + 1] - piy;
    float vz = pos_m[j * 3 + 2] - piz;
    float r = sqrtf(vx * vx + vy * vy + vz * vz);
    float rm = fmaxf(r, 1e-9f);
    float inv = 1.f / rm;
    float ux = vx * inv, uy = vy * inv, uz = vz * inv;
    float sh[L_DIM];
    sh[0] = 1.f; sh[1] = ux; sh[2] = uy; sh[3] = uz;
    sh[4] = ux * uy; sh[5] = uy * uz; sh[6] = 3.f * uz * uz - 1.f;
    sh[7] = ux * uz; sh[8] = ux * ux - uy * uy;
    // bessel via sin recurrence: sin(n t) = 2 cos(t) sin((n-1)t) - sin((n-2)t)
    float theta = 0.62831853071795864769f * r;  // pi/R_CUT
    float s1 = sinf(theta), c1 = cosf(theta);
    float coef = 0.632455532033675866f * inv;   // sqrt(2/R_CUT)/max(r,eps)
    float rd[R_DIM];
    float snm2 = 0.f, snm1 = s1;
    rd[0] = s1 * coef;
#pragma unroll
    for (int n = 2; n <= R_DIM; n++) {
      float sn = 2.f * c1 * snm1 - snm2;
      rd[n - 1] = sn * coef;
      snm2 = snm1; snm1 = sn;
    }
    float rw = 0.f;
#pragma unroll
    for (int p = 0; p < R_DIM; p++) rw = fmaf(rd[p], sW[p * F_DIM + f], rw);
    float tm = hWn[(size_t)j * F_DIM + f] * rw;
#pragma unroll
    for (int l = 0; l < L_DIM; l++) acc[l] = fmaf(sh[l], tm, acc[l]);
  }
#pragma unroll
  for (int l = 0; l < L_DIM; l++)
    upd_m[(size_t)i * DOUT_DIM + l * F_DIM + f] = acc[l];
}

// ---------------- final blend: in-place over fp32 h_local living in d_out region 0
__global__ __launch_bounds__(256) void combine_kernel(
    float* __restrict__ out0, const float* __restrict__ h_hier,
    const float* __restrict__ m_ws, const int* __restrict__ rank)
{
  size_t idx = (size_t)blockIdx.x * 256 + threadIdx.x;
  int n = (int)(idx / DOUT_DIM);
  int g = (int)(idx % DOUT_DIM);
  float mv = m_ws[n];
  float hl = out0[idx];
  int r = rank[n];
  float he = (r < K_SEL) ? h_hier[(size_t)r * DOUT_DIM + g] : 0.f;
  out0[idx] = (1.f - mv) * hl + mv * he;
}

extern "C" void kernel_launch(void* const* d_in, const int* in_sizes, int n_in,
                              void* d_out, int out_size, void* d_ws, size_t ws_size,
                              hipStream_t stream)
{
  const float* h         = (const float*)d_in[0];
  const float* pos       = (const float*)d_in[1];
  const float* edge_sh   = (const float*)d_in[2];
  const float* edge_feats= (const float*)d_in[3];
  const float* W_node_l  = (const float*)d_in[4];
  const float* W_rad_l   = (const float*)d_in[5];
  const float* W_prod_l  = (const float*)d_in[6];
  const float* ms_W1     = (const float*)d_in[7];
  const float* ms_b1     = (const float*)d_in[8];
  const float* ms_W2     = (const float*)d_in[9];
  const float* ms_b2     = (const float*)d_in[10];
  const float* vg_Wq     = (const float*)d_in[11];
  const float* vg_Wk     = (const float*)d_in[12];
  const float* W_node_h  = (const float*)d_in[13];
  const float* W_rad_h   = (const float*)d_in[14];
  const float* W_prod_h  = (const float*)d_in[15];
  const int*   eidx      = (const int*)d_in[16];

  // d_out is FP32 (reference outputs are float32): concat flat in return order.
  float* out    = (float*)d_out;
  float* out_hf = out;                                      // N*DOUT  (hosts fp32 h_local)
  float* out_Av = out + (size_t)N_NODES * DOUT_DIM;         // K*K
  float* out_m  = out_Av + (size_t)K_SEL * K_SEL;           // N
  float* out_mi = out_m + N_NODES;                          // K

  char* ws = (char*)d_ws;
  // Big arena: upd fp32 [0, 75.5MB); hW fp32 [75.5MB, 83.9MB).
  float* upd = (float*)ws;
  float* hW  = (float*)(ws + (size_t)N_NODES * DOUT_DIM * 4);
  // Small pool aliased over upd (valid once upd is dead, after the h_local GEMM).
  size_t off = 0;
  auto alloc = [&](size_t bytes) -> void* {
    void* p = ws + off;
    off += (bytes + 255) & ~(size_t)255;
    return p;
  };
  float* m_ws  = (float*)alloc((size_t)N_NODES * 4);
  int*   rank  = (int*)alloc((size_t)N_NODES * 4);
  int*   midx  = (int*)alloc((size_t)K_SEL * 4);
  unsigned long long* keys = (unsigned long long*)alloc((size_t)N_NODES * 8);
  unsigned char* adjm  = (unsigned char*)alloc((size_t)K_SEL * K_SEL);
  unsigned char* maskA = (unsigned char*)alloc((size_t)K_SEL * K_SEL);
  float* qbuf  = (float*)alloc((size_t)K_SEL * DA_DIM * 4);
  float* kbuf  = (float*)alloc((size_t)K_SEL * DA_DIM * 4);
  float* h_m   = (float*)alloc((size_t)K_SEL * DOUT_DIM * 4);
  float* pos_m = (float*)alloc((size_t)K_SEL * 3 * 4);
  float* hWn   = (float*)alloc((size_t)K_SEL * F_DIM * 4);
  float* upd_m = (float*)alloc((size_t)K_SEL * DOUT_DIM * 4);
  float* h_hier= (float*)alloc((size_t)K_SEL * DOUT_DIM * 4);

  // Phase A/B: hW = h @ W_node_l; scatter edges into upd (fp32 HW atomics)
  hipMemsetAsync(upd, 0, (size_t)N_NODES * DOUT_DIM * 4, stream);
  gemm_f32<<<dim3(1, N_NODES / 128), 256, 0, stream>>>(
      h, F_DIM, W_node_l, F_DIM, hW, F_DIM, N_NODES, F_DIM, F_DIM, nullptr, 0, 0);
  scatter_kernel<<<E_EDGES / 2, 256, 0, stream>>>(hW, edge_sh, edge_feats, W_rad_l, eidx, upd);

  // Phase C: h_local (fp32, directly into d_out region 0)
  gemm_f32<<<dim3(DOUT_DIM / 128, N_NODES / 128), 256, 0, stream>>>(
      upd, DOUT_DIM, W_prod_l, DOUT_DIM, out_hf, DOUT_DIM,
      N_NODES, DOUT_DIM, DOUT_DIM, h, F_DIM, F_DIM);

  // upd is dead from here; small pool (aliasing upd) becomes live.
  hipMemsetAsync(adjm, 0, (size_t)K_SEL * K_SEL, stream);
  gate_kernel<<<N_NODES / 4, 256, 0, stream>>>(out_hf, ms_W1, ms_b1, ms_W2, ms_b2, m_ws, out_m);
  topk_kernel<<<1, 1024, 0, stream>>>(m_ws, keys, midx, rank, out_mi);
  adj_kernel<<<E_EDGES / 256, 256, 0, stream>>>(eidx, rank, adjm);
  gather_kernel<<<K_SEL, 128, 0, stream>>>(out_hf, pos, midx, h_m, pos_m);
  qk_kernel<<<K_SEL, 128, 0, stream>>>(out_hf, midx, vg_Wq, vg_Wk, qbuf, kbuf);
  attn_kernel<<<dim3(K_SEL / 16, K_SEL / 16), dim3(16, 16), 0, stream>>>(qbuf, kbuf, maskA, out_Av);
  gemm_f32<<<dim3(1, K_SEL / 128), 256, 0, stream>>>(
      h_m, DOUT_DIM, W_node_h, F_DIM, hWn, F_DIM, K_SEL, F_DIM, DOUT_DIM, nullptr, 0, 0);
  hier_kernel<<<K_SEL, 128, 0, stream>>>(hWn, maskA, adjm, pos_m, W_rad_h, upd_m);
  gemm_f32<<<dim3(DOUT_DIM / 128, K_SEL / 128), 256, 0, stream>>>(
      upd_m, DOUT_DIM, W_prod_h, DOUT_DIM, h_hier, DOUT_DIM,
      K_SEL, DOUT_DIM, DOUT_DIM, h_m, DOUT_DIM, DOUT_DIM);
  combine_kernel<<<(N_NODES * DOUT_DIM) / 256, 256, 0, stream>>>(out_hf, h_hier, m_ws, rank);
}

// Round 4
// 1862.754 us; speedup vs baseline: 1.3519x; 1.3519x over previous
//
#include <hip/hip_runtime.h>
#include <hip/hip_bf16.h>
#include <stdint.h>

#define N_NODES 16384
#define E_EDGES 131072
#define F_DIM 128
#define L_DIM 9
#define R_DIM 8
#define DOUT_DIM 1152
#define K_SEL 1024
#define HID_DIM 64
#define DA_DIM 64

typedef unsigned short u16;
typedef __attribute__((ext_vector_type(8))) short bf16x8;
typedef __attribute__((ext_vector_type(4))) float f32x4;

static __device__ inline u16 f2bs(float x) {
  union { __hip_bfloat16 b; u16 s; } u;
  u.b = __float2bfloat16(x);
  return u.s;
}

// async global->LDS, 16B per lane. LDS dest must be waveBase + lane*16.
#define GLDS16(gsrc, ldst) __builtin_amdgcn_global_load_lds( \
    (__attribute__((address_space(1))) void*)(void*)(gsrc),  \
    (__attribute__((address_space(3))) void*)(ldst), 16, 0, 0)

// ================= MFMA GEMM: C(MxN,f32) = A(MxK,f32->bf16) * B^T(NxK,bf16) [+Add]
// 128x128 tile, BK=32, 256 thr = 4 waves, each wave 64x64 via 4x4 mfma_f32_16x16x32_bf16.
// A staged fp32 in LDS (XOR-swizzled 16B octs), converted to bf16 frags in VALU.
__global__ __launch_bounds__(256) void gemm_mfma(
    const float* __restrict__ A, const u16* __restrict__ Bt,
    float* __restrict__ C, int ldc, int M, int Nc, int Kc,
    const float* __restrict__ Add, int ldadd, int addW)
{
  __shared__ float Af[128 * 32];   // [m][oct^ (m&7)] 16KB
  __shared__ u16  Bs[128 * 32];    // [n][q ^ ((n>>1)&3)] 8KB
  const int tid = threadIdx.x;
  const int wave = tid >> 6, lane = tid & 63;
  const int wm = wave >> 1, wn = wave & 1;
  const int l15 = lane & 15, quad = lane >> 4;
  const int bm = blockIdx.y * 128, bn = blockIdx.x * 128;

  f32x4 acc[4][4];
#pragma unroll
  for (int i = 0; i < 4; i++)
#pragma unroll
    for (int j = 0; j < 4; j++) acc[i][j] = (f32x4)(0.f);

  for (int k0 = 0; k0 < Kc; k0 += 32) {
    __syncthreads();
    // A: 1024 16B-chunks, 4 issues. chunk c: row=c>>3, stored oct-pos op=c&7 holds global oct op^(row&7)
#pragma unroll
    for (int it = 0; it < 4; it++) {
      int c = it * 256 + tid;
      int row = c >> 3, op = c & 7;
      int oct = op ^ (row & 7);
      const float* g = A + (size_t)(bm + row) * Kc + k0 + oct * 4;
      GLDS16(g, &Af[c * 4]);
    }
    // B: 512 16B-chunks, 2 issues. chunk c: row=c>>2, qp=c&3 holds global q = qp ^ ((row>>1)&3)
#pragma unroll
    for (int it = 0; it < 2; it++) {
      int c = it * 256 + tid;
      int row = c >> 2, qp = c & 3;
      int q = qp ^ ((row >> 1) & 3);
      const u16* g = Bt + (size_t)(bn + row) * Kc + k0 + q * 8;
      GLDS16(g, &Bs[c * 8]);
    }
    __syncthreads();

    bf16x8 af[4], bfg[4];
#pragma unroll
    for (int mi = 0; mi < 4; mi++) {
      int m = wm * 64 + mi * 16 + l15;
      int o0 = (quad * 2) ^ (m & 7), o1 = (quad * 2 + 1) ^ (m & 7);
      float4 lo = *(const float4*)&Af[m * 32 + o0 * 4];
      float4 hi = *(const float4*)&Af[m * 32 + o1 * 4];
      bf16x8 r;
      r[0] = (short)f2bs(lo.x); r[1] = (short)f2bs(lo.y);
      r[2] = (short)f2bs(lo.z); r[3] = (short)f2bs(lo.w);
      r[4] = (short)f2bs(hi.x); r[5] = (short)f2bs(hi.y);
      r[6] = (short)f2bs(hi.z); r[7] = (short)f2bs(hi.w);
      af[mi] = r;
    }
#pragma unroll
    for (int ni = 0; ni < 4; ni++) {
      int n = wn * 64 + ni * 16 + l15;
      int q2 = quad ^ ((n >> 1) & 3);
      bfg[ni] = *(const bf16x8*)&Bs[n * 32 + q2 * 8];
    }
#pragma unroll
    for (int mi = 0; mi < 4; mi++)
#pragma unroll
      for (int ni = 0; ni < 4; ni++)
        acc[mi][ni] = __builtin_amdgcn_mfma_f32_16x16x32_bf16(af[mi], bfg[ni], acc[mi][ni], 0, 0, 0);
  }
  // epilogue: D row = quad*4+reg, col = lane&15  [m89/m91 C/D mapping]
#pragma unroll
  for (int mi = 0; mi < 4; mi++)
#pragma unroll
    for (int ni = 0; ni < 4; ni++)
#pragma unroll
      for (int r = 0; r < 4; r++) {
        int row = bm + wm * 64 + mi * 16 + quad * 4 + r;
        int col = bn + wn * 64 + ni * 16 + l15;
        float v = acc[mi][ni][r];
        if (Add != nullptr && col < addW) v += Add[(size_t)row * ldadd + col];
        C[(size_t)row * ldc + col] = v;
      }
}

// ================= transpose + bf16 cast: Bt[n][k] = bf16(W[k][n]), K,N mult of 32
__global__ __launch_bounds__(256) void transpose_bf16(
    const float* __restrict__ W, u16* __restrict__ Bt, int K, int N)
{
  __shared__ float t[32][33];
  const int n0 = blockIdx.x * 32, k0 = blockIdx.y * 32;
  const int tx = threadIdx.x & 31, ty = threadIdx.x >> 5;
  for (int r = ty; r < 32; r += 8) t[r][tx] = W[(size_t)(k0 + r) * N + n0 + tx];
  __syncthreads();
  for (int r = ty; r < 32; r += 8) Bt[(size_t)(n0 + r) * K + k0 + tx] = f2bs(t[tx][r]);
}

// ================= fp32 GEMM 128x128 (used for hW only)
#define BM 128
#define BN 128
#define BK 16
__global__ __launch_bounds__(256) void gemm_f32(
    const float* __restrict__ A, int lda,
    const float* __restrict__ B, int ldb,
    float* __restrict__ C, int ldc,
    int M, int Nc, int Kc,
    const float* __restrict__ Add, int ldadd, int addW)
{
  __shared__ float As[BK][BM + 1];
  __shared__ float Bs[BK][BN];
  const int tid = threadIdx.x;
  const int tx = tid & 15, ty = tid >> 4;
  const int bm = blockIdx.y * BM, bn = blockIdx.x * BN;
  float acc[8][8];
#pragma unroll
  for (int i = 0; i < 8; i++)
#pragma unroll
    for (int j = 0; j < 8; j++) acc[i][j] = 0.f;
  for (int k0 = 0; k0 < Kc; k0 += BK) {
    const int ac = tid & 15, ar0 = tid >> 4;
#pragma unroll
    for (int rr = 0; rr < 8; rr++) {
      int row = ar0 + rr * 16;
      As[ac][row] = A[(size_t)(bm + row) * lda + k0 + ac];
    }
    const int bc = tid & 127, br0 = tid >> 7;
#pragma unroll
    for (int rr = 0; rr < 8; rr++) {
      int kr = br0 + rr * 2;
      Bs[kr][bc] = B[(size_t)(k0 + kr) * ldb + bn + bc];
    }
    __syncthreads();
#pragma unroll
    for (int kk = 0; kk < BK; kk++) {
      float a[8], b[8];
#pragma unroll
      for (int i = 0; i < 8; i++) a[i] = As[kk][ty * 8 + i];
#pragma unroll
      for (int j = 0; j < 8; j++) b[j] = Bs[kk][tx * 8 + j];
#pragma unroll
      for (int i = 0; i < 8; i++)
#pragma unroll
        for (int j = 0; j < 8; j++) acc[i][j] = fmaf(a[i], b[j], acc[i][j]);
    }
    __syncthreads();
  }
#pragma unroll
  for (int i = 0; i < 8; i++) {
    int row = bm + ty * 8 + i;
#pragma unroll
    for (int j = 0; j < 8; j++) {
      int col = bn + tx * 8 + j;
      float v = acc[i][j];
      if (Add != nullptr && col < addW) v += Add[(size_t)row * ldadd + col];
      C[(size_t)row * ldc + col] = v;
    }
  }
}

// ================= fp32 GEMM 64x64, optional split-K (atomic accumulate when gridDim.z>1)
__global__ __launch_bounds__(256) void gemm64_f32(
    const float* __restrict__ A, int lda,
    const float* __restrict__ B, int ldb,
    float* __restrict__ C, int ldc,
    int M, int Nc, int Kc, int kPerSplit,
    const float* __restrict__ Add, int ldadd, int addW)
{
  __shared__ float As[16][65];
  __shared__ float Bs[16][64];
  const int tid = threadIdx.x;
  const int tx = tid & 15, ty = tid >> 4;
  const int bm = blockIdx.y * 64, bn = blockIdx.x * 64;
  const int kb = blockIdx.z * kPerSplit;
  const int ke = min(kb + kPerSplit, Kc);
  float acc[4][4];
#pragma unroll
  for (int i = 0; i < 4; i++)
#pragma unroll
    for (int j = 0; j < 4; j++) acc[i][j] = 0.f;
  for (int k0 = kb; k0 < ke; k0 += 16) {
    const int ac = tid & 15, ar = tid >> 4;
#pragma unroll
    for (int rr = 0; rr < 4; rr++) {
      int row = ar + rr * 16;
      As[ac][row] = A[(size_t)(bm + row) * lda + k0 + ac];
    }
    const int bc = tid & 63, br = tid >> 6;
#pragma unroll
    for (int rr = 0; rr < 4; rr++) {
      int kr = br + rr * 4;
      Bs[kr][bc] = B[(size_t)(k0 + kr) * ldb + bn + bc];
    }
    __syncthreads();
#pragma unroll
    for (int kk = 0; kk < 16; kk++) {
      float a[4], b[4];
#pragma unroll
      for (int i = 0; i < 4; i++) a[i] = As[kk][ty * 4 + i];
#pragma unroll
      for (int j = 0; j < 4; j++) b[j] = Bs[kk][tx * 4 + j];
#pragma unroll
      for (int i = 0; i < 4; i++)
#pragma unroll
        for (int j = 0; j < 4; j++) acc[i][j] = fmaf(a[i], b[j], acc[i][j]);
    }
    __syncthreads();
  }
#pragma unroll
  for (int i = 0; i < 4; i++) {
    int row = bm + ty * 4 + i;
#pragma unroll
    for (int j = 0; j < 4; j++) {
      int col = bn + tx * 4 + j;
      if (gridDim.z > 1) {
        atomicAdd(&C[(size_t)row * ldc + col], acc[i][j]);
      } else {
        float v = acc[i][j];
        if (Add != nullptr && col < addW) v += Add[(size_t)row * ldadd + col];
        C[(size_t)row * ldc + col] = v;
      }
    }
  }
}

// ================= edge scatter
__global__ __launch_bounds__(256) void scatter_kernel(
    const float* __restrict__ hW, const float* __restrict__ edge_sh,
    const float* __restrict__ edge_feats, const float* __restrict__ W_rad_l,
    const int* __restrict__ ei, float* __restrict__ upd)
{
  __shared__ float sWr[R_DIM * F_DIM];
  const int tid = threadIdx.x;
  for (int t = tid; t < R_DIM * F_DIM; t += 256) sWr[t] = W_rad_l[t];
  __syncthreads();
  const int f = tid & 127;
  const int sub = tid >> 7;
  const size_t e = (size_t)blockIdx.x * 2 + sub;
  const int s = ei[e], d = ei[E_EDGES + e];
  float rw = 0.f;
#pragma unroll
  for (int p = 0; p < R_DIM; p++)
    rw = fmaf(edge_feats[e * R_DIM + p], sWr[p * F_DIM + f], rw);
  const float tf = hW[(size_t)s * F_DIM + f] * rw;
  float* base = upd + (size_t)d * DOUT_DIM + f;
#pragma unroll
  for (int l = 0; l < L_DIM; l++)
    atomicAdd(base + l * F_DIM, edge_sh[e * L_DIM + l] * tf);
}

// ================= gating MLP on hs (fp32, ld=F_DIM)
__global__ __launch_bounds__(256) void gate_kernel(
    const float* __restrict__ hs, const float* __restrict__ W1,
    const float* __restrict__ b1, const float* __restrict__ W2,
    const float* __restrict__ b2, float* __restrict__ m_ws, float* __restrict__ m_out)
{
  __shared__ float sW1[F_DIM * HID_DIM];
  __shared__ float srow[4][F_DIM];
  const int tid = threadIdx.x;
  for (int t = tid; t < F_DIM * HID_DIM; t += 256) sW1[t] = W1[t];
  const int wave = tid >> 6, lane = tid & 63;
  const int n = blockIdx.x * 4 + wave;
  srow[wave][lane] = hs[(size_t)n * F_DIM + lane];
  srow[wave][lane + 64] = hs[(size_t)n * F_DIM + lane + 64];
  __syncthreads();
  float hid = b1[lane];
#pragma unroll 8
  for (int c = 0; c < F_DIM; c++) hid = fmaf(srow[wave][c], sW1[c * HID_DIM + lane], hid);
  hid = fmaxf(hid, 0.f);
  float v = hid * W2[lane];
#pragma unroll
  for (int off = 32; off > 0; off >>= 1) v += __shfl_down(v, off);
  if (lane == 0) {
    float mm = 1.f / (1.f + expf(-(v + b2[0])));
    m_ws[n] = mm;
    m_out[n] = mm;
  }
}

// ================= exact top-K + sort + rank (single block bitonic)
__global__ __launch_bounds__(1024) void topk_kernel(
    const float* __restrict__ m_ws,
    unsigned long long* __restrict__ keys,
    int* __restrict__ master_idx, int* __restrict__ rank,
    float* __restrict__ mi_out)
{
  __shared__ unsigned long long s[8192];
  const int tid = threadIdx.x;
  for (int i = tid; i < N_NODES; i += 1024) {
    unsigned mb = __float_as_uint(m_ws[i]);
    keys[i] = (((unsigned long long)mb) << 14) | (unsigned long long)(16383 - i);
  }
  __syncthreads();
  for (int ch = 0; ch < 2; ch++) {
    unsigned long long* g = keys + ch * 8192;
    for (int i = tid; i < 8192; i += 1024) s[i] = g[i];
    __syncthreads();
    for (int k = 2; k <= 8192; k <<= 1) {
      for (int j = k >> 1; j > 0; j >>= 1) {
        for (int i = tid; i < 8192; i += 1024) {
          int ixj = i ^ j;
          if (ixj > i) {
            unsigned long long a = s[i], b = s[ixj];
            bool up = ((i & k) == 0);
            if (up ? (a < b) : (a > b)) { s[i] = b; s[ixj] = a; }
          }
        }
        __syncthreads();
      }
    }
    for (int i = tid; i < 8192; i += 1024) g[i] = s[i];
    __syncthreads();
  }
  s[tid] = keys[tid];
  s[1024 + tid] = keys[8192 + (1023 - tid)];
  __syncthreads();
  for (int j = 1024; j > 0; j >>= 1) {
    for (int i = tid; i < 2048; i += 1024) {
      int ixj = i ^ j;
      if (ixj > i) {
        unsigned long long a = s[i], b = s[ixj];
        if (a < b) { s[i] = b; s[ixj] = a; }
      }
    }
    __syncthreads();
  }
  int myidx = 16383 - (int)(s[tid] & 0x3FFFull);
  __syncthreads();
  int* si = (int*)s;
  si[tid] = myidx;
  __syncthreads();
  for (int k = 2; k <= 1024; k <<= 1) {
    for (int j = k >> 1; j > 0; j >>= 1) {
      int i = tid, ixj = i ^ j;
      if (ixj > i) {
        int a = si[i], b = si[ixj];
        bool up = ((i & k) == 0);
        if (up ? (a > b) : (a < b)) { si[i] = b; si[ixj] = a; }
      }
      __syncthreads();
    }
  }
  int v = si[tid];
  master_idx[tid] = v;
  mi_out[tid] = (float)v;
  for (int i = tid; i < N_NODES; i += 1024) rank[i] = K_SEL;
  __syncthreads();
  rank[si[tid]] = tid;
}

// ================= induced adjacency
__global__ __launch_bounds__(256) void adj_kernel(
    const int* __restrict__ ei, const int* __restrict__ rank, unsigned char* __restrict__ adjm)
{
  int e = blockIdx.x * 256 + threadIdx.x;
  int rs = rank[ei[e]];
  int rd = rank[ei[E_EDGES + e]];
  if (rs < K_SEL && rd < K_SEL) adjm[(size_t)rs * K_SEL + rd] = 1;
}

// ================= gather master rows + positions
__global__ __launch_bounds__(128) void gather_kernel(
    const float* __restrict__ hl, const float* __restrict__ pos,
    const int* __restrict__ midx, float* __restrict__ h_m, float* __restrict__ pos_m)
{
  const int rI = blockIdx.x, t = threadIdx.x;
  const int mi = midx[rI];
  for (int c = t; c < DOUT_DIM; c += 128)
    h_m[(size_t)rI * DOUT_DIM + c] = hl[(size_t)mi * DOUT_DIM + c];
  if (t < 3) pos_m[rI * 3 + t] = pos[mi * 3 + t];
}

// ================= q/k projections from hs (ld=F_DIM) at master rows
__global__ __launch_bounds__(128) void qk_kernel(
    const float* __restrict__ hs, const int* __restrict__ midx,
    const float* __restrict__ Wq, const float* __restrict__ Wk,
    float* __restrict__ q, float* __restrict__ kk)
{
  __shared__ float row[F_DIM];
  const int i = blockIdx.x, t = threadIdx.x;
  const int mi = midx[i];
  row[t] = hs[(size_t)mi * F_DIM + t];
  __syncthreads();
  const int d = t & 63;
  const float* W = (t < 64) ? Wq : Wk;
  float acc = 0.f;
#pragma unroll 8
  for (int c = 0; c < F_DIM; c++) acc = fmaf(row[c], W[c * DA_DIM + d], acc);
  float* dst = (t < 64) ? q : kk;
  dst[(size_t)i * DA_DIM + d] = acc;
}

// ================= attention
__global__ __launch_bounds__(256) void attn_kernel(
    const float* __restrict__ q, const float* __restrict__ kk,
    unsigned char* __restrict__ maskA, float* __restrict__ Av)
{
  __shared__ float qs[16][DA_DIM], ks[16][DA_DIM];
  const int tx = threadIdx.x, ty = threadIdx.y;
  const int tid = ty * 16 + tx;
  const int i0 = blockIdx.y * 16, j0 = blockIdx.x * 16;
  for (int t = tid; t < 16 * DA_DIM; t += 256) {
    int rr = t >> 6, cc = t & 63;
    qs[rr][cc] = q[(size_t)(i0 + rr) * DA_DIM + cc];
    ks[rr][cc] = kk[(size_t)(j0 + rr) * DA_DIM + cc];
  }
  __syncthreads();
  float acc = 0.f;
#pragma unroll
  for (int d2 = 0; d2 < DA_DIM; d2++) acc = fmaf(qs[ty][d2], ks[tx][d2], acc);
  float sgl = 1.f / (1.f + expf(-acc * 0.125f));
  size_t o = (size_t)(i0 + ty) * K_SEL + (j0 + tx);
  bool big = sgl > 0.5f;
  maskA[o] = big ? 1 : 0;
  Av[o] = big ? sgl : 0.f;
}

// ================= hierarchical accumulation
__global__ __launch_bounds__(128) void hier_kernel(
    const float* __restrict__ hWn, const unsigned char* __restrict__ maskA,
    const unsigned char* __restrict__ adjm, const float* __restrict__ pos_m,
    const float* __restrict__ W_rad_h, float* __restrict__ upd_m)
{
  __shared__ float sW[R_DIM * F_DIM];
  const int i = blockIdx.x;
  const int f = threadIdx.x;
  for (int t = f; t < R_DIM * F_DIM; t += 128) sW[t] = W_rad_h[t];
  __syncthreads();
  const float pix = pos_m[i * 3 + 0], piy = pos_m[i * 3 + 1], piz = pos_m[i * 3 + 2];
  float acc[L_DIM];
#pragma unroll
  for (int l = 0; l < L_DIM; l++) acc[l] = 0.f;
  for (int j = 0; j < K_SEL; j++) {
    bool e = (j != i) && (adjm[(size_t)j * K_SEL + i] | maskA[(size_t)j * K_SEL + i] |
                          maskA[(size_t)i * K_SEL + j]);
    if (!e) continue;
    float vx = pos_m[j * 3 + 0] - pix;
    float vy = pos_m[j * 3 + 1] - piy;
    float vz = pos_m[j * 3 + 2] - piz;
    float r = sqrtf(vx * vx + vy * vy + vz * vz);
    float rm = fmaxf(r, 1e-9f);
    float inv = 1.f / rm;
    float ux = vx * inv, uy = vy * inv, uz = vz * inv;
    float sh[L_DIM];
    sh[0] = 1.f; sh[1] = ux; sh[2] = uy; sh[3] = uz;
    sh[4] = ux * uy; sh[5] = uy * uz; sh[6] = 3.f * uz * uz - 1.f;
    sh[7] = ux * uz; sh[8] = ux * ux - uy * uy;
    float theta = 0.62831853071795864769f * r;
    float s1 = sinf(theta), c1 = cosf(theta);
    float coef = 0.632455532033675866f * inv;
    float rd[R_DIM];
    float snm2 = 0.f, snm1 = s1;
    rd[0] = s1 * coef;
#pragma unroll
    for (int n = 2; n <= R_DIM; n++) {
      float sn = 2.f * c1 * snm1 - snm2;
      rd[n - 1] = sn * coef;
      snm2 = snm1; snm1 = sn;
    }
    float rw = 0.f;
#pragma unroll
    for (int p = 0; p < R_DIM; p++) rw = fmaf(rd[p], sW[p * F_DIM + f], rw);
    float tm = hWn[(size_t)j * F_DIM + f] * rw;
#pragma unroll
    for (int l = 0; l < L_DIM; l++) acc[l] = fmaf(sh[l], tm, acc[l]);
  }
#pragma unroll
  for (int l = 0; l < L_DIM; l++)
    upd_m[(size_t)i * DOUT_DIM + l * F_DIM + f] = acc[l];
}

// ================= final blend (in-place over h_local in d_out region 0)
__global__ __launch_bounds__(256) void combine_kernel(
    float* __restrict__ out0, const float* __restrict__ h_hier,
    const float* __restrict__ m_ws, const int* __restrict__ rank)
{
  size_t idx = (size_t)blockIdx.x * 256 + threadIdx.x;
  int n = (int)(idx / DOUT_DIM);
  int g = (int)(idx % DOUT_DIM);
  float mv = m_ws[n];
  float hl = out0[idx];
  int r = rank[n];
  float he = (r < K_SEL) ? h_hier[(size_t)r * DOUT_DIM + g] : 0.f;
  out0[idx] = (1.f - mv) * hl + mv * he;
}

extern "C" void kernel_launch(void* const* d_in, const int* in_sizes, int n_in,
                              void* d_out, int out_size, void* d_ws, size_t ws_size,
                              hipStream_t stream)
{
  const float* h         = (const float*)d_in[0];
  const float* pos       = (const float*)d_in[1];
  const float* edge_sh   = (const float*)d_in[2];
  const float* edge_feats= (const float*)d_in[3];
  const float* W_node_l  = (const float*)d_in[4];
  const float* W_rad_l   = (const float*)d_in[5];
  const float* W_prod_l  = (const float*)d_in[6];
  const float* ms_W1     = (const float*)d_in[7];
  const float* ms_b1     = (const float*)d_in[8];
  const float* ms_W2     = (const float*)d_in[9];
  const float* ms_b2     = (const float*)d_in[10];
  const float* vg_Wq     = (const float*)d_in[11];
  const float* vg_Wk     = (const float*)d_in[12];
  const float* W_node_h  = (const float*)d_in[13];
  const float* W_rad_h   = (const float*)d_in[14];
  const float* W_prod_h  = (const float*)d_in[15];
  const int*   eidx      = (const int*)d_in[16];

  float* out    = (float*)d_out;
  float* out_hf = out;                                      // N*DOUT (hosts h_local)
  float* out_Av = out + (size_t)N_NODES * DOUT_DIM;         // K*K   (hosts Btl until attn)
  float* out_m  = out_Av + (size_t)K_SEL * K_SEL;           // N
  float* out_mi = out_m + N_NODES;                          // K

  char* ws = (char*)d_ws;
  // Phase 1: upd fp32 [0, 75.5MB); hW then hs at [75.5, 83.9MB). Peak = 83.9MB.
  float* upd = (float*)ws;
  float* hW  = (float*)(ws + (size_t)N_NODES * DOUT_DIM * 4);
  float* hs  = hW;  // hW dead after scatter; hs written after
  // Btl (bf16 W_prod_l^T, 2.6MB) borrows the A_virtual out region (written later by attn)
  u16* Btl = (u16*)out_Av;
  // Phase 2 small pool aliases dead upd (valid after the big MFMA GEMM)
  size_t off = 0;
  auto alloc = [&](size_t bytes) -> void* {
    void* p = ws + off;
    off += (bytes + 255) & ~(size_t)255;
    return p;
  };
  float* m_ws  = (float*)alloc((size_t)N_NODES * 4);
  int*   rank  = (int*)alloc((size_t)N_NODES * 4);
  int*   midx  = (int*)alloc((size_t)K_SEL * 4);
  unsigned long long* keys = (unsigned long long*)alloc((size_t)N_NODES * 8);
  unsigned char* adjm  = (unsigned char*)alloc((size_t)K_SEL * K_SEL);
  unsigned char* maskA = (unsigned char*)alloc((size_t)K_SEL * K_SEL);
  float* qbuf  = (float*)alloc((size_t)K_SEL * DA_DIM * 4);
  float* kbuf  = (float*)alloc((size_t)K_SEL * DA_DIM * 4);
  float* h_m   = (float*)alloc((size_t)K_SEL * DOUT_DIM * 4);
  float* pos_m = (float*)alloc((size_t)K_SEL * 3 * 4);
  float* hWn   = (float*)alloc((size_t)K_SEL * F_DIM * 4);
  float* upd_m = (float*)alloc((size_t)K_SEL * DOUT_DIM * 4);
  float* h_hier= (float*)alloc((size_t)K_SEL * DOUT_DIM * 4);
  u16*   Bth   = (u16*)alloc((size_t)DOUT_DIM * DOUT_DIM * 2);

  // ---- Phase 1: message passing
  hipMemsetAsync(upd, 0, (size_t)N_NODES * DOUT_DIM * 4, stream);
  transpose_bf16<<<dim3(DOUT_DIM / 32, DOUT_DIM / 32), 256, 0, stream>>>(
      W_prod_l, Btl, DOUT_DIM, DOUT_DIM);
  gemm_f32<<<dim3(1, N_NODES / 128), 256, 0, stream>>>(
      h, F_DIM, W_node_l, F_DIM, hW, F_DIM, N_NODES, F_DIM, F_DIM, nullptr, 0, 0);
  scatter_kernel<<<E_EDGES / 2, 256, 0, stream>>>(hW, edge_sh, edge_feats, W_rad_l, eidx, upd);
  // hs (fp32-exact gate input) = upd @ W_prod_l[:, :128] + h
  gemm64_f32<<<dim3(F_DIM / 64, N_NODES / 64, 1), 256, 0, stream>>>(
      upd, DOUT_DIM, W_prod_l, DOUT_DIM, hs, F_DIM,
      N_NODES, F_DIM, DOUT_DIM, DOUT_DIM, h, F_DIM, F_DIM);
  // h_local (MFMA bf16) into d_out region 0
  gemm_mfma<<<dim3(DOUT_DIM / 128, N_NODES / 128), 256, 0, stream>>>(
      upd, Btl, out_hf, DOUT_DIM, N_NODES, DOUT_DIM, DOUT_DIM, h, F_DIM, F_DIM);

  // ---- Phase 2: upd dead; small pool live; Btl (out_Av) dead
  hipMemsetAsync(adjm, 0, (size_t)K_SEL * K_SEL, stream);
  transpose_bf16<<<dim3(DOUT_DIM / 32, DOUT_DIM / 32), 256, 0, stream>>>(
      W_prod_h, Bth, DOUT_DIM, DOUT_DIM);
  gate_kernel<<<N_NODES / 4, 256, 0, stream>>>(hs, ms_W1, ms_b1, ms_W2, ms_b2, m_ws, out_m);
  topk_kernel<<<1, 1024, 0, stream>>>(m_ws, keys, midx, rank, out_mi);
  adj_kernel<<<E_EDGES / 256, 256, 0, stream>>>(eidx, rank, adjm);
  gather_kernel<<<K_SEL, 128, 0, stream>>>(out_hf, pos, midx, h_m, pos_m);
  qk_kernel<<<K_SEL, 128, 0, stream>>>(hs, midx, vg_Wq, vg_Wk, qbuf, kbuf);
  attn_kernel<<<dim3(K_SEL / 16, K_SEL / 16), dim3(16, 16), 0, stream>>>(qbuf, kbuf, maskA, out_Av);
  // hWn = h_m @ W_node_h  (split-K over 4, atomic accumulate)
  hipMemsetAsync(hWn, 0, (size_t)K_SEL * F_DIM * 4, stream);
  gemm64_f32<<<dim3(F_DIM / 64, K_SEL / 64, 4), 256, 0, stream>>>(
      h_m, DOUT_DIM, W_node_h, F_DIM, hWn, F_DIM,
      K_SEL, F_DIM, DOUT_DIM, DOUT_DIM / 4, nullptr, 0, 0);
  hier_kernel<<<K_SEL, 128, 0, stream>>>(hWn, maskA, adjm, pos_m, W_rad_h, upd_m);
  // h_hier = upd_m @ W_prod_h + h_m  (MFMA)
  gemm_mfma<<<dim3(DOUT_DIM / 128, K_SEL / 128), 256, 0, stream>>>(
      upd_m, Bth, h_hier, DOUT_DIM, K_SEL, DOUT_DIM, DOUT_DIM, h_m, DOUT_DIM, DOUT_DIM);
  combine_kernel<<<(N_NODES * DOUT_DIM) / 256, 256, 0, stream>>>(out_hf, h_hier, m_ws, rank);
}

// Round 5
// 1003.813 us; speedup vs baseline: 2.5087x; 1.8557x over previous
//
#include <hip/hip_runtime.h>
#include <hip/hip_bf16.h>
#include <stdint.h>

#define N_NODES 16384
#define E_EDGES 131072
#define F_DIM 128
#define L_DIM 9
#define R_DIM 8
#define DOUT_DIM 1152
#define K_SEL 1024
#define HID_DIM 64
#define DA_DIM 64

typedef unsigned short u16;
typedef __attribute__((ext_vector_type(8))) short bf16x8;
typedef __attribute__((ext_vector_type(4))) float f32x4;

static __device__ inline u16 f2bs(float x) {
  union { __hip_bfloat16 b; u16 s; } u;
  u.b = __float2bfloat16(x);
  return u.s;
}

// async global->LDS, 16B per lane. LDS dest must be waveBase + lane*16.
#define GLDS16(gsrc, ldst) __builtin_amdgcn_global_load_lds( \
    (__attribute__((address_space(1))) void*)(void*)(gsrc),  \
    (__attribute__((address_space(3))) void*)(ldst), 16, 0, 0)

// ================= MFMA GEMM: C(MxN,f32) = A(MxK,f32->bf16) * B^T(NxK,bf16) [+Add]
// 128x128 tile, BK=32, 256 thr = 4 waves, each wave 64x64 via 4x4 mfma_f32_16x16x32_bf16.
__global__ __launch_bounds__(256) void gemm_mfma(
    const float* __restrict__ A, const u16* __restrict__ Bt,
    float* __restrict__ C, int ldc, int M, int Nc, int Kc,
    const float* __restrict__ Add, int ldadd, int addW)
{
  __shared__ float Af[128 * 32];   // [m][oct ^ (m&7)]
  __shared__ u16  Bs[128 * 32];    // [n][q ^ ((n>>1)&3)]
  const int tid = threadIdx.x;
  const int wave = tid >> 6, lane = tid & 63;
  const int wm = wave >> 1, wn = wave & 1;
  const int l15 = lane & 15, quad = lane >> 4;
  const int bm = blockIdx.y * 128, bn = blockIdx.x * 128;

  f32x4 acc[4][4];
#pragma unroll
  for (int i = 0; i < 4; i++)
#pragma unroll
    for (int j = 0; j < 4; j++) acc[i][j] = (f32x4)(0.f);

  for (int k0 = 0; k0 < Kc; k0 += 32) {
    __syncthreads();
#pragma unroll
    for (int it = 0; it < 4; it++) {
      int c = it * 256 + tid;
      int row = c >> 3, op = c & 7;
      int oct = op ^ (row & 7);
      const float* g = A + (size_t)(bm + row) * Kc + k0 + oct * 4;
      GLDS16(g, &Af[c * 4]);
    }
#pragma unroll
    for (int it = 0; it < 2; it++) {
      int c = it * 256 + tid;
      int row = c >> 2, qp = c & 3;
      int q = qp ^ ((row >> 1) & 3);
      const u16* g = Bt + (size_t)(bn + row) * Kc + k0 + q * 8;
      GLDS16(g, &Bs[c * 8]);
    }
    __syncthreads();

    bf16x8 af[4], bfg[4];
#pragma unroll
    for (int mi = 0; mi < 4; mi++) {
      int m = wm * 64 + mi * 16 + l15;
      int o0 = (quad * 2) ^ (m & 7), o1 = (quad * 2 + 1) ^ (m & 7);
      float4 lo = *(const float4*)&Af[m * 32 + o0 * 4];
      float4 hi = *(const float4*)&Af[m * 32 + o1 * 4];
      bf16x8 r;
      r[0] = (short)f2bs(lo.x); r[1] = (short)f2bs(lo.y);
      r[2] = (short)f2bs(lo.z); r[3] = (short)f2bs(lo.w);
      r[4] = (short)f2bs(hi.x); r[5] = (short)f2bs(hi.y);
      r[6] = (short)f2bs(hi.z); r[7] = (short)f2bs(hi.w);
      af[mi] = r;
    }
#pragma unroll
    for (int ni = 0; ni < 4; ni++) {
      int n = wn * 64 + ni * 16 + l15;
      int q2 = quad ^ ((n >> 1) & 3);
      bfg[ni] = *(const bf16x8*)&Bs[n * 32 + q2 * 8];
    }
#pragma unroll
    for (int mi = 0; mi < 4; mi++)
#pragma unroll
      for (int ni = 0; ni < 4; ni++)
        acc[mi][ni] = __builtin_amdgcn_mfma_f32_16x16x32_bf16(af[mi], bfg[ni], acc[mi][ni], 0, 0, 0);
  }
#pragma unroll
  for (int mi = 0; mi < 4; mi++)
#pragma unroll
    for (int ni = 0; ni < 4; ni++)
#pragma unroll
      for (int r = 0; r < 4; r++) {
        int row = bm + wm * 64 + mi * 16 + quad * 4 + r;
        int col = bn + wn * 64 + ni * 16 + l15;
        float v = acc[mi][ni][r];
        if (Add != nullptr && col < addW) v += Add[(size_t)row * ldadd + col];
        C[(size_t)row * ldc + col] = v;
      }
}

// ================= transpose + bf16 cast
__global__ __launch_bounds__(256) void transpose_bf16(
    const float* __restrict__ W, u16* __restrict__ Bt, int K, int N)
{
  __shared__ float t[32][33];
  const int n0 = blockIdx.x * 32, k0 = blockIdx.y * 32;
  const int tx = threadIdx.x & 31, ty = threadIdx.x >> 5;
  for (int r = ty; r < 32; r += 8) t[r][tx] = W[(size_t)(k0 + r) * N + n0 + tx];
  __syncthreads();
  for (int r = ty; r < 32; r += 8) Bt[(size_t)(n0 + r) * K + k0 + tx] = f2bs(t[tx][r]);
}

// ================= fp32 GEMM 128x128 (hW)
#define BM 128
#define BN 128
#define BK 16
__global__ __launch_bounds__(256) void gemm_f32(
    const float* __restrict__ A, int lda,
    const float* __restrict__ B, int ldb,
    float* __restrict__ C, int ldc,
    int M, int Nc, int Kc,
    const float* __restrict__ Add, int ldadd, int addW)
{
  __shared__ float As[BK][BM + 1];
  __shared__ float Bs[BK][BN];
  const int tid = threadIdx.x;
  const int tx = tid & 15, ty = tid >> 4;
  const int bm = blockIdx.y * BM, bn = blockIdx.x * BN;
  float acc[8][8];
#pragma unroll
  for (int i = 0; i < 8; i++)
#pragma unroll
    for (int j = 0; j < 8; j++) acc[i][j] = 0.f;
  for (int k0 = 0; k0 < Kc; k0 += BK) {
    const int ac = tid & 15, ar0 = tid >> 4;
#pragma unroll
    for (int rr = 0; rr < 8; rr++) {
      int row = ar0 + rr * 16;
      As[ac][row] = A[(size_t)(bm + row) * lda + k0 + ac];
    }
    const int bc = tid & 127, br0 = tid >> 7;
#pragma unroll
    for (int rr = 0; rr < 8; rr++) {
      int kr = br0 + rr * 2;
      Bs[kr][bc] = B[(size_t)(k0 + kr) * ldb + bn + bc];
    }
    __syncthreads();
#pragma unroll
    for (int kk = 0; kk < BK; kk++) {
      float a[8], b[8];
#pragma unroll
      for (int i = 0; i < 8; i++) a[i] = As[kk][ty * 8 + i];
#pragma unroll
      for (int j = 0; j < 8; j++) b[j] = Bs[kk][tx * 8 + j];
#pragma unroll
      for (int i = 0; i < 8; i++)
#pragma unroll
        for (int j = 0; j < 8; j++) acc[i][j] = fmaf(a[i], b[j], acc[i][j]);
    }
    __syncthreads();
  }
#pragma unroll
  for (int i = 0; i < 8; i++) {
    int row = bm + ty * 8 + i;
#pragma unroll
    for (int j = 0; j < 8; j++) {
      int col = bn + tx * 8 + j;
      float v = acc[i][j];
      if (Add != nullptr && col < addW) v += Add[(size_t)row * ldadd + col];
      C[(size_t)row * ldc + col] = v;
    }
  }
}

// ================= fp32 GEMM 64x64, optional split-K
__global__ __launch_bounds__(256) void gemm64_f32(
    const float* __restrict__ A, int lda,
    const float* __restrict__ B, int ldb,
    float* __restrict__ C, int ldc,
    int M, int Nc, int Kc, int kPerSplit,
    const float* __restrict__ Add, int ldadd, int addW)
{
  __shared__ float As[16][65];
  __shared__ float Bs[16][64];
  const int tid = threadIdx.x;
  const int tx = tid & 15, ty = tid >> 4;
  const int bm = blockIdx.y * 64, bn = blockIdx.x * 64;
  const int kb = blockIdx.z * kPerSplit;
  const int ke = min(kb + kPerSplit, Kc);
  float acc[4][4];
#pragma unroll
  for (int i = 0; i < 4; i++)
#pragma unroll
    for (int j = 0; j < 4; j++) acc[i][j] = 0.f;
  for (int k0 = kb; k0 < ke; k0 += 16) {
    const int ac = tid & 15, ar = tid >> 4;
#pragma unroll
    for (int rr = 0; rr < 4; rr++) {
      int row = ar + rr * 16;
      As[ac][row] = A[(size_t)(bm + row) * lda + k0 + ac];
    }
    const int bc = tid & 63, br = tid >> 6;
#pragma unroll
    for (int rr = 0; rr < 4; rr++) {
      int kr = br + rr * 4;
      Bs[kr][bc] = B[(size_t)(k0 + kr) * ldb + bn + bc];
    }
    __syncthreads();
#pragma unroll
    for (int kk = 0; kk < 16; kk++) {
      float a[4], b[4];
#pragma unroll
      for (int i = 0; i < 4; i++) a[i] = As[kk][ty * 4 + i];
#pragma unroll
      for (int j = 0; j < 4; j++) b[j] = Bs[kk][tx * 4 + j];
#pragma unroll
      for (int i = 0; i < 4; i++)
#pragma unroll
        for (int j = 0; j < 4; j++) acc[i][j] = fmaf(a[i], b[j], acc[i][j]);
    }
    __syncthreads();
  }
#pragma unroll
  for (int i = 0; i < 4; i++) {
    int row = bm + ty * 4 + i;
#pragma unroll
    for (int j = 0; j < 4; j++) {
      int col = bn + tx * 4 + j;
      if (gridDim.z > 1) {
        atomicAdd(&C[(size_t)row * ldc + col], acc[i][j]);
      } else {
        float v = acc[i][j];
        if (Add != nullptr && col < addW) v += Add[(size_t)row * ldadd + col];
        C[(size_t)row * ldc + col] = v;
      }
    }
  }
}

// ================= CSR build: count / scan / fill
__global__ __launch_bounds__(256) void count_kernel(
    const int* __restrict__ ei, int* __restrict__ counts)
{
  int e = blockIdx.x * 256 + threadIdx.x;
  atomicAdd(&counts[ei[E_EDGES + e]], 1);
}

__global__ __launch_bounds__(1024) void scan_kernel(
    const int* __restrict__ counts, int* __restrict__ offsets, int* __restrict__ cursor)
{
  __shared__ int part[1024];
  const int t = threadIdx.x;
  const int base = t * 16;
  int loc[16];
  int s = 0;
#pragma unroll
  for (int k = 0; k < 16; k++) { loc[k] = counts[base + k]; s += loc[k]; }
  part[t] = s;
  __syncthreads();
  for (int d = 1; d < 1024; d <<= 1) {
    int v = (t >= d) ? part[t - d] : 0;
    __syncthreads();
    part[t] += v;
    __syncthreads();
  }
  int run = part[t] - s;  // exclusive prefix
#pragma unroll
  for (int k = 0; k < 16; k++) {
    offsets[base + k] = run;
    cursor[base + k] = run;
    run += loc[k];
  }
}

__global__ __launch_bounds__(256) void fill_kernel(
    const int* __restrict__ ei, int* __restrict__ cursor, int* __restrict__ elist)
{
  int e = blockIdx.x * 256 + threadIdx.x;
  int d = ei[E_EDGES + e];
  int p = atomicAdd(&cursor[d], 1);
  elist[p] = e;
}

// ================= atomic-free edge accumulation: block per dst node
__global__ __launch_bounds__(128) void gather_accum_kernel(
    const float* __restrict__ hW, const float* __restrict__ edge_sh,
    const float* __restrict__ edge_feats, const float* __restrict__ W_rad_l,
    const int* __restrict__ ei, const int* __restrict__ offsets,
    const int* __restrict__ counts, const int* __restrict__ elist,
    float* __restrict__ upd)
{
  __shared__ float sWr[R_DIM * F_DIM];
  const int d = blockIdx.x, f = threadIdx.x;
  for (int t = f; t < R_DIM * F_DIM; t += 128) sWr[t] = W_rad_l[t];
  __syncthreads();
  const int b = offsets[d], n = counts[d];
  float acc[L_DIM];
#pragma unroll
  for (int l = 0; l < L_DIM; l++) acc[l] = 0.f;
  for (int k = 0; k < n; k++) {
    const int e = elist[b + k];
    const int s = ei[e];
    float rw = 0.f;
#pragma unroll
    for (int p = 0; p < R_DIM; p++)
      rw = fmaf(edge_feats[(size_t)e * R_DIM + p], sWr[p * F_DIM + f], rw);
    const float tf = hW[(size_t)s * F_DIM + f] * rw;
#pragma unroll
    for (int l = 0; l < L_DIM; l++)
      acc[l] = fmaf(edge_sh[(size_t)e * L_DIM + l], tf, acc[l]);
  }
#pragma unroll
  for (int l = 0; l < L_DIM; l++)
    upd[(size_t)d * DOUT_DIM + l * F_DIM + f] = acc[l];
}

// ================= gating MLP on hs (fp32, ld=F_DIM)
__global__ __launch_bounds__(256) void gate_kernel(
    const float* __restrict__ hs, const float* __restrict__ W1,
    const float* __restrict__ b1, const float* __restrict__ W2,
    const float* __restrict__ b2, float* __restrict__ m_ws, float* __restrict__ m_out)
{
  __shared__ float sW1[F_DIM * HID_DIM];
  __shared__ float srow[4][F_DIM];
  const int tid = threadIdx.x;
  for (int t = tid; t < F_DIM * HID_DIM; t += 256) sW1[t] = W1[t];
  const int wave = tid >> 6, lane = tid & 63;
  const int n = blockIdx.x * 4 + wave;
  srow[wave][lane] = hs[(size_t)n * F_DIM + lane];
  srow[wave][lane + 64] = hs[(size_t)n * F_DIM + lane + 64];
  __syncthreads();
  float hid = b1[lane];
#pragma unroll 8
  for (int c = 0; c < F_DIM; c++) hid = fmaf(srow[wave][c], sW1[c * HID_DIM + lane], hid);
  hid = fmaxf(hid, 0.f);
  float v = hid * W2[lane];
#pragma unroll
  for (int off = 32; off > 0; off >>= 1) v += __shfl_down(v, off);
  if (lane == 0) {
    float mm = 1.f / (1.f + expf(-(v + b2[0])));
    m_ws[n] = mm;
    m_out[n] = mm;
  }
}

// ================= exact top-K + sort + rank (single block bitonic)
__global__ __launch_bounds__(1024) void topk_kernel(
    const float* __restrict__ m_ws,
    unsigned long long* __restrict__ keys,
    int* __restrict__ master_idx, int* __restrict__ rank,
    float* __restrict__ mi_out)
{
  __shared__ unsigned long long s[8192];
  const int tid = threadIdx.x;
  for (int i = tid; i < N_NODES; i += 1024) {
    unsigned mb = __float_as_uint(m_ws[i]);
    keys[i] = (((unsigned long long)mb) << 14) | (unsigned long long)(16383 - i);
  }
  __syncthreads();
  for (int ch = 0; ch < 2; ch++) {
    unsigned long long* g = keys + ch * 8192;
    for (int i = tid; i < 8192; i += 1024) s[i] = g[i];
    __syncthreads();
    for (int k = 2; k <= 8192; k <<= 1) {
      for (int j = k >> 1; j > 0; j >>= 1) {
        for (int i = tid; i < 8192; i += 1024) {
          int ixj = i ^ j;
          if (ixj > i) {
            unsigned long long a = s[i], b = s[ixj];
            bool up = ((i & k) == 0);
            if (up ? (a < b) : (a > b)) { s[i] = b; s[ixj] = a; }
          }
        }
        __syncthreads();
      }
    }
    for (int i = tid; i < 8192; i += 1024) g[i] = s[i];
    __syncthreads();
  }
  s[tid] = keys[tid];
  s[1024 + tid] = keys[8192 + (1023 - tid)];
  __syncthreads();
  for (int j = 1024; j > 0; j >>= 1) {
    for (int i = tid; i < 2048; i += 1024) {
      int ixj = i ^ j;
      if (ixj > i) {
        unsigned long long a = s[i], b = s[ixj];
        if (a < b) { s[i] = b; s[ixj] = a; }
      }
    }
    __syncthreads();
  }
  int myidx = 16383 - (int)(s[tid] & 0x3FFFull);
  __syncthreads();
  int* si = (int*)s;
  si[tid] = myidx;
  __syncthreads();
  for (int k = 2; k <= 1024; k <<= 1) {
    for (int j = k >> 1; j > 0; j >>= 1) {
      int i = tid, ixj = i ^ j;
      if (ixj > i) {
        int a = si[i], b = si[ixj];
        bool up = ((i & k) == 0);
        if (up ? (a > b) : (a < b)) { si[i] = b; si[ixj] = a; }
      }
      __syncthreads();
    }
  }
  int v = si[tid];
  master_idx[tid] = v;
  mi_out[tid] = (float)v;
  for (int i = tid; i < N_NODES; i += 1024) rank[i] = K_SEL;
  __syncthreads();
  rank[si[tid]] = tid;
}

// ================= induced adjacency
__global__ __launch_bounds__(256) void adj_kernel(
    const int* __restrict__ ei, const int* __restrict__ rank, unsigned char* __restrict__ adjm)
{
  int e = blockIdx.x * 256 + threadIdx.x;
  int rs = rank[ei[e]];
  int rd = rank[ei[E_EDGES + e]];
  if (rs < K_SEL && rd < K_SEL) adjm[(size_t)rs * K_SEL + rd] = 1;
}

// ================= gather master rows + positions
__global__ __launch_bounds__(128) void gather_kernel(
    const float* __restrict__ hl, const float* __restrict__ pos,
    const int* __restrict__ midx, float* __restrict__ h_m, float* __restrict__ pos_m)
{
  const int rI = blockIdx.x, t = threadIdx.x;
  const int mi = midx[rI];
  for (int c = t; c < DOUT_DIM; c += 128)
    h_m[(size_t)rI * DOUT_DIM + c] = hl[(size_t)mi * DOUT_DIM + c];
  if (t < 3) pos_m[rI * 3 + t] = pos[mi * 3 + t];
}

// ================= q/k projections from hs at master rows
__global__ __launch_bounds__(128) void qk_kernel(
    const float* __restrict__ hs, const int* __restrict__ midx,
    const float* __restrict__ Wq, const float* __restrict__ Wk,
    float* __restrict__ q, float* __restrict__ kk)
{
  __shared__ float row[F_DIM];
  const int i = blockIdx.x, t = threadIdx.x;
  const int mi = midx[i];
  row[t] = hs[(size_t)mi * F_DIM + t];
  __syncthreads();
  const int d = t & 63;
  const float* W = (t < 64) ? Wq : Wk;
  float acc = 0.f;
#pragma unroll 8
  for (int c = 0; c < F_DIM; c++) acc = fmaf(row[c], W[c * DA_DIM + d], acc);
  float* dst = (t < 64) ? q : kk;
  dst[(size_t)i * DA_DIM + d] = acc;
}

// ================= attention
__global__ __launch_bounds__(256) void attn_kernel(
    const float* __restrict__ q, const float* __restrict__ kk,
    unsigned char* __restrict__ maskA, float* __restrict__ Av)
{
  __shared__ float qs[16][DA_DIM], ks[16][DA_DIM];
  const int tx = threadIdx.x, ty = threadIdx.y;
  const int tid = ty * 16 + tx;
  const int i0 = blockIdx.y * 16, j0 = blockIdx.x * 16;
  for (int t = tid; t < 16 * DA_DIM; t += 256) {
    int rr = t >> 6, cc = t & 63;
    qs[rr][cc] = q[(size_t)(i0 + rr) * DA_DIM + cc];
    ks[rr][cc] = kk[(size_t)(j0 + rr) * DA_DIM + cc];
  }
  __syncthreads();
  float acc = 0.f;
#pragma unroll
  for (int d2 = 0; d2 < DA_DIM; d2++) acc = fmaf(qs[ty][d2], ks[tx][d2], acc);
  float sgl = 1.f / (1.f + expf(-acc * 0.125f));
  size_t o = (size_t)(i0 + ty) * K_SEL + (j0 + tx);
  bool big = sgl > 0.5f;
  maskA[o] = big ? 1 : 0;
  Av[o] = big ? sgl : 0.f;
}

// ================= per-i active-j list (compaction; order-free)
__global__ __launch_bounds__(256) void listbuild_kernel(
    const unsigned char* __restrict__ adjm, const unsigned char* __restrict__ maskA,
    u16* __restrict__ list, int* __restrict__ nj)
{
  __shared__ int cnt;
  const int i = blockIdx.x, tid = threadIdx.x;
  if (tid == 0) cnt = 0;
  __syncthreads();
#pragma unroll
  for (int jt = 0; jt < 4; jt++) {
    int j = jt * 256 + tid;
    bool e = (j != i) && (adjm[(size_t)j * K_SEL + i] | maskA[(size_t)j * K_SEL + i] |
                          maskA[(size_t)i * K_SEL + j]);
    if (e) {
      int p = atomicAdd(&cnt, 1);
      list[(size_t)i * K_SEL + p] = (u16)j;
    }
  }
  __syncthreads();
  if (tid == 0) nj[i] = cnt;
}

// ================= hier v2: geometry once per pair (LDS), 4-way j-parallel f-work
__global__ __launch_bounds__(512) void hier2_kernel(
    const float* __restrict__ hWn, const float* __restrict__ pos_m,
    const float* __restrict__ W_rad_h, const u16* __restrict__ list,
    const int* __restrict__ nj, float* __restrict__ upd_m)
{
  __shared__ float sW[R_DIM * F_DIM];
  __shared__ float gsm[128][20];   // [pair][sh0..8, rd0..7, pad]
  __shared__ int sj[128];
  __shared__ float red[3][L_DIM][F_DIM];
  const int tid = threadIdx.x;
  const int i = blockIdx.x;
  const int f = tid & 127, jsub = tid >> 7;
  for (int t = tid; t < R_DIM * F_DIM; t += 512) sW[t] = W_rad_h[t];
  const float pix = pos_m[i * 3 + 0], piy = pos_m[i * 3 + 1], piz = pos_m[i * 3 + 2];
  float acc[L_DIM];
#pragma unroll
  for (int l = 0; l < L_DIM; l++) acc[l] = 0.f;
  const int n = nj[i];
  for (int c0 = 0; c0 < n; c0 += 128) {
    const int cnt = min(128, n - c0);
    __syncthreads();
    if (tid < cnt) {
      const int j = list[(size_t)i * K_SEL + c0 + tid];
      sj[tid] = j;
      float vx = pos_m[j * 3 + 0] - pix;
      float vy = pos_m[j * 3 + 1] - piy;
      float vz = pos_m[j * 3 + 2] - piz;
      float r = sqrtf(vx * vx + vy * vy + vz * vz);
      float rm = fmaxf(r, 1e-9f);
      float inv = 1.f / rm;
      float ux = vx * inv, uy = vy * inv, uz = vz * inv;
      gsm[tid][0] = 1.f; gsm[tid][1] = ux; gsm[tid][2] = uy; gsm[tid][3] = uz;
      gsm[tid][4] = ux * uy; gsm[tid][5] = uy * uz;
      gsm[tid][6] = 3.f * uz * uz - 1.f;
      gsm[tid][7] = ux * uz; gsm[tid][8] = ux * ux - uy * uy;
      float theta = 0.62831853071795864769f * r;  // pi/R_CUT
      float s1 = sinf(theta), c1 = cosf(theta);
      float coef = 0.632455532033675866f * inv;   // sqrt(2/R_CUT)/max(r,eps)
      float snm2 = 0.f, snm1 = s1;
      gsm[tid][9] = s1 * coef;
#pragma unroll
      for (int nn = 2; nn <= R_DIM; nn++) {
        float sn = 2.f * c1 * snm1 - snm2;
        gsm[tid][8 + nn] = sn * coef;
        snm2 = snm1; snm1 = sn;
      }
      gsm[tid][17] = 0.f; gsm[tid][18] = 0.f; gsm[tid][19] = 0.f;
    }
    __syncthreads();
    for (int t = jsub; t < cnt; t += 4) {
      const int j = sj[t];
      const float hw = hWn[(size_t)j * F_DIM + f];
      float4 g0 = *(const float4*)&gsm[t][0];    // sh0..3
      float4 g1 = *(const float4*)&gsm[t][4];    // sh4..7
      float4 g2 = *(const float4*)&gsm[t][8];    // sh8, rd0..2
      float4 g3 = *(const float4*)&gsm[t][12];   // rd3..6
      float  g4 = gsm[t][16];                    // rd7
      float rw = g2.y * sW[0 * F_DIM + f];
      rw = fmaf(g2.z, sW[1 * F_DIM + f], rw);
      rw = fmaf(g2.w, sW[2 * F_DIM + f], rw);
      rw = fmaf(g3.x, sW[3 * F_DIM + f], rw);
      rw = fmaf(g3.y, sW[4 * F_DIM + f], rw);
      rw = fmaf(g3.z, sW[5 * F_DIM + f], rw);
      rw = fmaf(g3.w, sW[6 * F_DIM + f], rw);
      rw = fmaf(g4,   sW[7 * F_DIM + f], rw);
      const float tm = hw * rw;
      acc[0] = fmaf(g0.x, tm, acc[0]); acc[1] = fmaf(g0.y, tm, acc[1]);
      acc[2] = fmaf(g0.z, tm, acc[2]); acc[3] = fmaf(g0.w, tm, acc[3]);
      acc[4] = fmaf(g1.x, tm, acc[4]); acc[5] = fmaf(g1.y, tm, acc[5]);
      acc[6] = fmaf(g1.z, tm, acc[6]); acc[7] = fmaf(g1.w, tm, acc[7]);
      acc[8] = fmaf(g2.x, tm, acc[8]);
    }
  }
  __syncthreads();
  if (jsub > 0) {
#pragma unroll
    for (int l = 0; l < L_DIM; l++) red[jsub - 1][l][f] = acc[l];
  }
  __syncthreads();
  if (jsub == 0) {
#pragma unroll
    for (int l = 0; l < L_DIM; l++) {
      float v = acc[l] + red[0][l][f] + red[1][l][f] + red[2][l][f];
      upd_m[(size_t)i * DOUT_DIM + l * F_DIM + f] = v;
    }
  }
}

// ================= final blend (in-place over h_local in d_out region 0)
__global__ __launch_bounds__(256) void combine_kernel(
    float* __restrict__ out0, const float* __restrict__ h_hier,
    const float* __restrict__ m_ws, const int* __restrict__ rank)
{
  size_t idx = (size_t)blockIdx.x * 256 + threadIdx.x;
  int n = (int)(idx / DOUT_DIM);
  int g = (int)(idx % DOUT_DIM);
  float mv = m_ws[n];
  float hl = out0[idx];
  int r = rank[n];
  float he = (r < K_SEL) ? h_hier[(size_t)r * DOUT_DIM + g] : 0.f;
  out0[idx] = (1.f - mv) * hl + mv * he;
}

extern "C" void kernel_launch(void* const* d_in, const int* in_sizes, int n_in,
                              void* d_out, int out_size, void* d_ws, size_t ws_size,
                              hipStream_t stream)
{
  const float* h         = (const float*)d_in[0];
  const float* pos       = (const float*)d_in[1];
  const float* edge_sh   = (const float*)d_in[2];
  const float* edge_feats= (const float*)d_in[3];
  const float* W_node_l  = (const float*)d_in[4];
  const float* W_rad_l   = (const float*)d_in[5];
  const float* W_prod_l  = (const float*)d_in[6];
  const float* ms_W1     = (const float*)d_in[7];
  const float* ms_b1     = (const float*)d_in[8];
  const float* ms_W2     = (const float*)d_in[9];
  const float* ms_b2     = (const float*)d_in[10];
  const float* vg_Wq     = (const float*)d_in[11];
  const float* vg_Wk     = (const float*)d_in[12];
  const float* W_node_h  = (const float*)d_in[13];
  const float* W_rad_h   = (const float*)d_in[14];
  const float* W_prod_h  = (const float*)d_in[15];
  const int*   eidx      = (const int*)d_in[16];

  float* out    = (float*)d_out;
  float* out_hf = out;
  float* out_Av = out + (size_t)N_NODES * DOUT_DIM;
  float* out_m  = out_Av + (size_t)K_SEL * K_SEL;
  float* out_mi = out_m + N_NODES;

  char* ws = (char*)d_ws;
  // Phase 1: upd [0, 75.5MB); hW/hs [75.5, 83.9MB). Peak = 83.9MB (proven).
  float* upd = (float*)ws;
  float* hW  = (float*)(ws + (size_t)N_NODES * DOUT_DIM * 4);
  float* hs  = hW;  // hW dead after gather_accum; hs written after
  // Btl + CSR borrow the A_virtual out region (4MB, dead until attn writes it).
  u16* Btl = (u16*)out_Av;                                       // 2.65 MB
  char* csr = (char*)out_Av + (((size_t)DOUT_DIM * DOUT_DIM * 2 + 255) & ~(size_t)255);
  int* counts  = (int*)csr;                                      // 64 KB
  int* offsets = counts + N_NODES;                               // 64 KB
  int* cursor  = offsets + N_NODES;                              // 64 KB
  int* elist   = cursor + N_NODES;                               // 512 KB  (total 3.4MB < 4MB)
  // Phase 2 small pool aliases dead upd.
  size_t off = 0;
  auto alloc = [&](size_t bytes) -> void* {
    void* p = ws + off;
    off += (bytes + 255) & ~(size_t)255;
    return p;
  };
  float* m_ws  = (float*)alloc((size_t)N_NODES * 4);
  int*   rank  = (int*)alloc((size_t)N_NODES * 4);
  int*   midx  = (int*)alloc((size_t)K_SEL * 4);
  unsigned long long* keys = (unsigned long long*)alloc((size_t)N_NODES * 8);
  unsigned char* adjm  = (unsigned char*)alloc((size_t)K_SEL * K_SEL);
  unsigned char* maskA = (unsigned char*)alloc((size_t)K_SEL * K_SEL);
  float* qbuf  = (float*)alloc((size_t)K_SEL * DA_DIM * 4);
  float* kbuf  = (float*)alloc((size_t)K_SEL * DA_DIM * 4);
  float* h_m   = (float*)alloc((size_t)K_SEL * DOUT_DIM * 4);
  float* pos_m = (float*)alloc((size_t)K_SEL * 3 * 4);
  float* hWn   = (float*)alloc((size_t)K_SEL * F_DIM * 4);
  float* upd_m = (float*)alloc((size_t)K_SEL * DOUT_DIM * 4);
  float* h_hier= (float*)alloc((size_t)K_SEL * DOUT_DIM * 4);
  u16*   Bth   = (u16*)alloc((size_t)DOUT_DIM * DOUT_DIM * 2);
  u16*   jlist = (u16*)alloc((size_t)K_SEL * K_SEL * 2);
  int*   njbuf = (int*)alloc((size_t)K_SEL * 4);

  // ---- Phase 1: message passing (CSR, atomic-free)
  hipMemsetAsync(counts, 0, (size_t)N_NODES * 4, stream);
  transpose_bf16<<<dim3(DOUT_DIM / 32, DOUT_DIM / 32), 256, 0, stream>>>(
      W_prod_l, Btl, DOUT_DIM, DOUT_DIM);
  gemm_f32<<<dim3(1, N_NODES / 128), 256, 0, stream>>>(
      h, F_DIM, W_node_l, F_DIM, hW, F_DIM, N_NODES, F_DIM, F_DIM, nullptr, 0, 0);
  count_kernel<<<E_EDGES / 256, 256, 0, stream>>>(eidx, counts);
  scan_kernel<<<1, 1024, 0, stream>>>(counts, offsets, cursor);
  fill_kernel<<<E_EDGES / 256, 256, 0, stream>>>(eidx, cursor, elist);
  gather_accum_kernel<<<N_NODES, 128, 0, stream>>>(
      hW, edge_sh, edge_feats, W_rad_l, eidx, offsets, counts, elist, upd);
  // hs (fp32-exact gate input) = upd @ W_prod_l[:, :128] + h
  gemm64_f32<<<dim3(F_DIM / 64, N_NODES / 64, 1), 256, 0, stream>>>(
      upd, DOUT_DIM, W_prod_l, DOUT_DIM, hs, F_DIM,
      N_NODES, F_DIM, DOUT_DIM, DOUT_DIM, h, F_DIM, F_DIM);
  // h_local (MFMA bf16) into d_out region 0
  gemm_mfma<<<dim3(DOUT_DIM / 128, N_NODES / 128), 256, 0, stream>>>(
      upd, Btl, out_hf, DOUT_DIM, N_NODES, DOUT_DIM, DOUT_DIM, h, F_DIM, F_DIM);

  // ---- Phase 2
  hipMemsetAsync(adjm, 0, (size_t)K_SEL * K_SEL, stream);
  transpose_bf16<<<dim3(DOUT_DIM / 32, DOUT_DIM / 32), 256, 0, stream>>>(
      W_prod_h, Bth, DOUT_DIM, DOUT_DIM);
  gate_kernel<<<N_NODES / 4, 256, 0, stream>>>(hs, ms_W1, ms_b1, ms_W2, ms_b2, m_ws, out_m);
  topk_kernel<<<1, 1024, 0, stream>>>(m_ws, keys, midx, rank, out_mi);
  adj_kernel<<<E_EDGES / 256, 256, 0, stream>>>(eidx, rank, adjm);
  gather_kernel<<<K_SEL, 128, 0, stream>>>(out_hf, pos, midx, h_m, pos_m);
  qk_kernel<<<K_SEL, 128, 0, stream>>>(hs, midx, vg_Wq, vg_Wk, qbuf, kbuf);
  attn_kernel<<<dim3(K_SEL / 16, K_SEL / 16), dim3(16, 16), 0, stream>>>(qbuf, kbuf, maskA, out_Av);
  listbuild_kernel<<<K_SEL, 256, 0, stream>>>(adjm, maskA, jlist, njbuf);
  hipMemsetAsync(hWn, 0, (size_t)K_SEL * F_DIM * 4, stream);
  gemm64_f32<<<dim3(F_DIM / 64, K_SEL / 64, 4), 256, 0, stream>>>(
      h_m, DOUT_DIM, W_node_h, F_DIM, hWn, F_DIM,
      K_SEL, F_DIM, DOUT_DIM, DOUT_DIM / 4, nullptr, 0, 0);
  hier2_kernel<<<K_SEL, 512, 0, stream>>>(hWn, pos_m, W_rad_h, jlist, njbuf, upd_m);
  gemm_mfma<<<dim3(DOUT_DIM / 128, K_SEL / 128), 256, 0, stream>>>(
      upd_m, Bth, h_hier, DOUT_DIM, K_SEL, DOUT_DIM, DOUT_DIM, h_m, DOUT_DIM, DOUT_DIM);
  combine_kernel<<<(N_NODES * DOUT_DIM) / 256, 256, 0, stream>>>(out_hf, h_hier, m_ws, rank);
}